// Round 2
// baseline (375.423 us; speedup 1.0000x reference)
//
#include <hip/hip_runtime.h>
#include <hip/hip_bf16.h>
#include <cstdint>
#include <cstddef>

using bf16 = __hip_bfloat16;
typedef __attribute__((ext_vector_type(8))) short bf16x8;   // 8 bf16 = 4 VGPRs (MFMA A/B frag)
typedef __attribute__((ext_vector_type(4))) float f32x4;    // MFMA C/D frag

#define B_    4
#define LQ_   1024
#define LKV_  2048
#define QDIM_ 1024
#define KDIM_ 768
#define ODIM_ 1024
#define H_    16
#define HD_   64

// ---------------------------------------------------------------------------
// async global -> LDS, 16B per lane (wave-uniform LDS base + lane*16)
// ---------------------------------------------------------------------------
__device__ __forceinline__ void async_cp16(const void* g, void* l) {
  __builtin_amdgcn_global_load_lds(
      (const __attribute__((address_space(1))) void*)g,
      (__attribute__((address_space(3))) void*)l, 16, 0, 0);
}

// ---------------------------------------------------------------------------
// mask normalize: input may be 1-byte bools (JAX bool memcpy) or int32 0/1.
// Detect: for int32 0/1 data, every byte at offset%4!=0 within the first n
// bytes is zero; for n=8192 random bools P(all zero) ~ 2^-3072. Never reads
// past n bytes (valid under both interpretations). One block.
// ---------------------------------------------------------------------------
__global__ void mask_prep(const void* __restrict__ mraw, int* __restrict__ mout,
                          int n) {
  __shared__ int fmt8;
  const int tid = threadIdx.x;
  if (tid == 0) fmt8 = 0;
  __syncthreads();
  const unsigned char* b = (const unsigned char*)mraw;
  int local = 0;
  for (int i = tid; i < n; i += 256)
    if ((i & 3) != 0 && b[i] != 0) local = 1;
  if (local) atomicOr(&fmt8, 1);
  __syncthreads();
  const int is8 = fmt8;
  const int* w = (const int*)mraw;
  for (int i = tid; i < n; i += 256)
    mout[i] = is8 ? (int)b[i] : (w[i] != 0);
}

// ---------------------------------------------------------------------------
// fp32 -> bf16 elementwise convert (vectorized: float4 in, 4x bf16 out)
// ---------------------------------------------------------------------------
struct alignas(8) bf4 { bf16 x[4]; };

__global__ void cvt_f32_to_bf16(const float* __restrict__ in,
                                bf16* __restrict__ out, int n4) {
  int i = blockIdx.x * blockDim.x + threadIdx.x;
  if (i >= n4) return;
  float4 v = reinterpret_cast<const float4*>(in)[i];
  bf4 r;
  r.x[0] = __float2bfloat16(v.x);
  r.x[1] = __float2bfloat16(v.y);
  r.x[2] = __float2bfloat16(v.z);
  r.x[3] = __float2bfloat16(v.w);
  *reinterpret_cast<bf4*>(out + (size_t)i * 4) = r;
}

// ---------------------------------------------------------------------------
// weight transpose + convert: W [K][N] fp32  ->  WT [N][K] bf16
// ---------------------------------------------------------------------------
__global__ void wtrans(const float* __restrict__ W, bf16* __restrict__ WT,
                       int K, int N) {
  __shared__ bf16 t[64][65];
  const int n0 = blockIdx.x * 64, k0 = blockIdx.y * 64;
  const int tid = threadIdx.x;
#pragma unroll
  for (int i = 0; i < 16; ++i) {
    int idx = tid + i * 256;
    int nn = idx & 63, kk = idx >> 6;
    t[kk][nn] = __float2bfloat16(W[(size_t)(k0 + kk) * N + n0 + nn]);
  }
  __syncthreads();
#pragma unroll
  for (int i = 0; i < 16; ++i) {
    int idx = tid + i * 256;
    int kk = idx & 63, nn = idx >> 6;
    WT[(size_t)(n0 + nn) * K + k0 + kk] = t[kk][nn];
  }
}

// ---------------------------------------------------------------------------
// V transpose: vp [B][LKV][ODIM] bf16 -> vT [B][H][HD][LKV] bf16
// ---------------------------------------------------------------------------
__global__ void vtrans(const bf16* __restrict__ vp, bf16* __restrict__ vT) {
  __shared__ bf16 t[64][65];
  const int kv0 = blockIdx.x * 64, h = blockIdx.y, b = blockIdx.z;
  const int tid = threadIdx.x;
#pragma unroll
  for (int i = 0; i < 16; ++i) {
    int idx = tid + i * 256;
    int hd = idx & 63, kv = idx >> 6;
    t[kv][hd] = vp[(size_t)(b * LKV_ + kv0 + kv) * ODIM_ + h * HD_ + hd];
  }
  __syncthreads();
#pragma unroll
  for (int i = 0; i < 16; ++i) {
    int idx = tid + i * 256;
    int kv = idx & 63, nn = idx >> 6;
    vT[(size_t)((b * H_ + h) * HD_ + nn) * LKV_ + kv0 + kv] = t[kv][nn];
  }
}

// ---------------------------------------------------------------------------
// GEMM: C[M][N] = A[M][K] @ BT[N][K]^T + bias
// 128x128 tile, BK=64, 256 threads (4 waves, 2x2), 16x16x32 bf16 MFMA.
// LDS staged via global_load_lds(16B) with pre-swizzled source; ds_read_b128
// with XOR swizzle (byte ^= (row&7)<<4) -> ~2-way conflicts (free).
// ---------------------------------------------------------------------------
template <int OUT_BF16>
__launch_bounds__(256, 2)
__global__ void gemm_bt(const bf16* __restrict__ A, const bf16* __restrict__ BT,
                        const float* __restrict__ bias, void* __restrict__ Cout,
                        int M, int N, int K) {
  __shared__ bf16 As[128 * 64];
  __shared__ bf16 Bs[128 * 64];
  const int tid = threadIdx.x;
  const int lane = tid & 63, w = tid >> 6;
  const int wr = w >> 1, wc = w & 1;
  const int lr = lane & 15, lk = lane >> 4;
  const int m0 = blockIdx.y * 128, n0 = blockIdx.x * 128;

  f32x4 acc[4][4];
#pragma unroll
  for (int m = 0; m < 4; ++m)
#pragma unroll
    for (int n = 0; n < 4; ++n) acc[m][n] = (f32x4){0.f, 0.f, 0.f, 0.f};

  const int nk = K >> 6;
  for (int kt = 0; kt < nk; ++kt) {
    const int k0 = kt << 6;
#pragma unroll
    for (int i = 0; i < 4; ++i) {           // stage A tile: 128 rows x 64 bf16
      const int c = tid + i * 256;
      const int row = c >> 3, cc = c & 7;
      const int sc = cc ^ (row & 7);        // pre-swizzle global source chunk
      async_cp16(A + (size_t)(m0 + row) * K + k0 + sc * 8, As + c * 8);
    }
#pragma unroll
    for (int i = 0; i < 4; ++i) {           // stage B^T tile: 128 rows x 64 bf16
      const int c = tid + i * 256;
      const int row = c >> 3, cc = c & 7;
      const int sc = cc ^ (row & 7);
      async_cp16(BT + (size_t)(n0 + row) * K + k0 + sc * 8, Bs + c * 8);
    }
    asm volatile("s_waitcnt vmcnt(0)" ::: "memory");
    __syncthreads();

    bf16x8 af[4][2], bfr[4][2];
#pragma unroll
    for (int m = 0; m < 4; ++m)
#pragma unroll
      for (int ks = 0; ks < 2; ++ks) {
        const int r = wr * 64 + m * 16 + lr;
        af[m][ks] = *(const bf16x8*)((const char*)As + r * 128 +
                                     ((ks * 64 + lk * 16) ^ ((r & 7) << 4)));
      }
#pragma unroll
    for (int n = 0; n < 4; ++n)
#pragma unroll
      for (int ks = 0; ks < 2; ++ks) {
        const int r = wc * 64 + n * 16 + lr;
        bfr[n][ks] = *(const bf16x8*)((const char*)Bs + r * 128 +
                                      ((ks * 64 + lk * 16) ^ ((r & 7) << 4)));
      }
#pragma unroll
    for (int m = 0; m < 4; ++m)
#pragma unroll
      for (int n = 0; n < 4; ++n)
#pragma unroll
        for (int ks = 0; ks < 2; ++ks)
          acc[m][n] = __builtin_amdgcn_mfma_f32_16x16x32_bf16(
              af[m][ks], bfr[n][ks], acc[m][n], 0, 0, 0);
    __syncthreads();
  }

  // epilogue: C/D layout col = lane&15, row = (lane>>4)*4 + reg
#pragma unroll
  for (int m = 0; m < 4; ++m)
#pragma unroll
    for (int n = 0; n < 4; ++n)
#pragma unroll
      for (int r4 = 0; r4 < 4; ++r4) {
        const int row = m0 + wr * 64 + m * 16 + lk * 4 + r4;
        const int col = n0 + wc * 64 + n * 16 + lr;
        float v = acc[m][n][r4] + bias[col];
        if (OUT_BF16)
          ((bf16*)Cout)[(size_t)row * N + col] = __float2bfloat16(v);
        else
          ((float*)Cout)[(size_t)row * N + col] = v;
      }
}

// ---------------------------------------------------------------------------
// Flash attention: block = (qtile of 128 rows, head, batch), 4 waves x 32 rows.
// qp [B][LQ][ODIM], kp [B][LKV][ODIM] (head h cols h*64..), vT [B][H][HD][LKV].
// mask[b][kv] != 0 -> masked (-1e30). Online softmax, P through swizzled LDS.
// ---------------------------------------------------------------------------
__launch_bounds__(256, 2)
__global__ void attn_kernel(const bf16* __restrict__ qp,
                            const bf16* __restrict__ kp,
                            const bf16* __restrict__ vT,
                            const int* __restrict__ mask,
                            bf16* __restrict__ att) {
  __shared__ bf16 Ks[128 * 64];    // [kv][hd] swizzled, 16KB
  __shared__ bf16 Vts[64 * 128];   // [hd][kv] swizzled, 16KB
  __shared__ bf16 Ps[128 * 128];   // [q][kv] swizzled, 32KB
  const int tid = threadIdx.x;
  const int lane = tid & 63, w = tid >> 6;
  const int lr = lane & 15, lk = lane >> 4;
  const int qt = blockIdx.x, h = blockIdx.y, b = blockIdx.z;
  const int q0 = qt * 128;

  // Q fragments
  bf16x8 qf[2][2];
#pragma unroll
  for (int qm = 0; qm < 2; ++qm)
#pragma unroll
    for (int ks = 0; ks < 2; ++ks) {
      const int qrow = q0 + w * 32 + qm * 16 + lr;
      qf[qm][ks] = *(const bf16x8*)(qp + (size_t)(b * LQ_ + qrow) * ODIM_ +
                                    h * HD_ + ks * 32 + lk * 8);
    }

  float m_run[2][4], l_run[2][4];
  f32x4 oacc[2][4];
#pragma unroll
  for (int qm = 0; qm < 2; ++qm)
#pragma unroll
    for (int r = 0; r < 4; ++r) {
      m_run[qm][r] = -1e30f;
      l_run[qm][r] = 0.f;
    }
#pragma unroll
  for (int qm = 0; qm < 2; ++qm)
#pragma unroll
    for (int n2 = 0; n2 < 4; ++n2) oacc[qm][n2] = (f32x4){0.f, 0.f, 0.f, 0.f};

  for (int t = 0; t < LKV_ / 128; ++t) {
    const int kv0 = t * 128;
    // stage K tile [128 kv][64 hd]
#pragma unroll
    for (int i = 0; i < 4; ++i) {
      const int c = tid + i * 256;
      const int row = c >> 3, cc = c & 7, sc = cc ^ (row & 7);
      async_cp16(kp + (size_t)(b * LKV_ + kv0 + row) * ODIM_ + h * HD_ + sc * 8,
                 Ks + c * 8);
    }
    // stage V^T tile [64 hd][128 kv]
#pragma unroll
    for (int i = 0; i < 4; ++i) {
      const int c = tid + i * 256;
      const int row = c >> 4, cc = c & 15, sc = cc ^ (row & 7);
      async_cp16(vT + (size_t)((b * H_ + h) * HD_ + row) * LKV_ + kv0 + sc * 8,
                 Vts + c * 8);
    }
    asm volatile("s_waitcnt vmcnt(0)" ::: "memory");
    __syncthreads();

    // S = Q @ K^T  (per wave: 32 q rows x 128 kv)
    bf16x8 kf[8][2];
#pragma unroll
    for (int n = 0; n < 8; ++n)
#pragma unroll
      for (int ks = 0; ks < 2; ++ks) {
        const int r = n * 16 + lr;
        kf[n][ks] = *(const bf16x8*)((const char*)Ks + r * 128 +
                                     ((ks * 64 + lk * 16) ^ ((r & 7) << 4)));
      }
    f32x4 s[2][8];
#pragma unroll
    for (int qm = 0; qm < 2; ++qm)
#pragma unroll
      for (int n = 0; n < 8; ++n) s[qm][n] = (f32x4){0.f, 0.f, 0.f, 0.f};
#pragma unroll
    for (int qm = 0; qm < 2; ++qm)
#pragma unroll
      for (int n = 0; n < 8; ++n)
#pragma unroll
        for (int ks = 0; ks < 2; ++ks)
          s[qm][n] = __builtin_amdgcn_mfma_f32_16x16x32_bf16(
              qf[qm][ks], kf[n][ks], s[qm][n], 0, 0, 0);

    // scale + mask
    int mk[8];
#pragma unroll
    for (int n = 0; n < 8; ++n) mk[n] = mask[b * LKV_ + kv0 + n * 16 + lr];
#pragma unroll
    for (int qm = 0; qm < 2; ++qm)
#pragma unroll
      for (int n = 0; n < 8; ++n)
#pragma unroll
        for (int r = 0; r < 4; ++r) {
          float v = s[qm][n][r] * 0.125f;
          s[qm][n][r] = mk[n] ? -1e30f : v;
        }

    // online softmax per q row (row = lk*4 + r within frag; cols across lr)
#pragma unroll
    for (int qm = 0; qm < 2; ++qm)
#pragma unroll
      for (int r = 0; r < 4; ++r) {
        float mx = -1e30f;
#pragma unroll
        for (int n = 0; n < 8; ++n) mx = fmaxf(mx, s[qm][n][r]);
        mx = fmaxf(mx, __shfl_xor(mx, 1));
        mx = fmaxf(mx, __shfl_xor(mx, 2));
        mx = fmaxf(mx, __shfl_xor(mx, 4));
        mx = fmaxf(mx, __shfl_xor(mx, 8));
        const float mnew = fmaxf(m_run[qm][r], mx);
        const float alpha = __expf(m_run[qm][r] - mnew);
        m_run[qm][r] = mnew;
        float rs = 0.f;
#pragma unroll
        for (int n = 0; n < 8; ++n) {
          float p = __expf(s[qm][n][r] - mnew);
          s[qm][n][r] = p;
          rs += p;
        }
        rs += __shfl_xor(rs, 1);
        rs += __shfl_xor(rs, 2);
        rs += __shfl_xor(rs, 4);
        rs += __shfl_xor(rs, 8);
        l_run[qm][r] = l_run[qm][r] * alpha + rs;
#pragma unroll
        for (int n2 = 0; n2 < 4; ++n2) oacc[qm][n2][r] *= alpha;
      }

    // write P to LDS (bf16, swizzled)
#pragma unroll
    for (int qm = 0; qm < 2; ++qm)
#pragma unroll
      for (int n = 0; n < 8; ++n)
#pragma unroll
        for (int r = 0; r < 4; ++r) {
          const int qrow = w * 32 + qm * 16 + lk * 4 + r;
          const int cb = (n * 32 + lr * 2) ^ ((qrow & 7) << 4);
          *(bf16*)((char*)Ps + qrow * 256 + cb) = __float2bfloat16(s[qm][n][r]);
        }
    __syncthreads();

    // O += P @ V   (A = P frag from LDS, B = V^T frag from LDS)
#pragma unroll
    for (int qm = 0; qm < 2; ++qm)
#pragma unroll
      for (int ks = 0; ks < 4; ++ks) {
        const int r = w * 32 + qm * 16 + lr;
        bf16x8 pa = *(const bf16x8*)((const char*)Ps + r * 256 +
                                     ((ks * 64 + lk * 16) ^ ((r & 7) << 4)));
#pragma unroll
        for (int n2 = 0; n2 < 4; ++n2) {
          const int hd = n2 * 16 + lr;
          bf16x8 vb = *(const bf16x8*)((const char*)Vts + hd * 256 +
                                       ((ks * 64 + lk * 16) ^ ((hd & 7) << 4)));
          oacc[qm][n2] = __builtin_amdgcn_mfma_f32_16x16x32_bf16(
              pa, vb, oacc[qm][n2], 0, 0, 0);
        }
      }
    __syncthreads();
  }

  // epilogue: divide by l, store bf16 to att [B][LQ][ODIM]
#pragma unroll
  for (int qm = 0; qm < 2; ++qm)
#pragma unroll
    for (int n2 = 0; n2 < 4; ++n2)
#pragma unroll
      for (int r = 0; r < 4; ++r) {
        const int qrow = q0 + w * 32 + qm * 16 + lk * 4 + r;
        const int col = h * HD_ + n2 * 16 + lr;
        const float v = oacc[qm][n2][r] / l_run[qm][r];
        att[(size_t)(b * LQ_ + qrow) * ODIM_ + col] = __float2bfloat16(v);
      }
}

// ---------------------------------------------------------------------------
extern "C" void kernel_launch(void* const* d_in, const int* in_sizes, int n_in,
                              void* d_out, int out_size, void* d_ws,
                              size_t ws_size, hipStream_t stream) {
  const float* query = (const float*)d_in[0];
  const float* key   = (const float*)d_in[1];
  const float* value = (const float*)d_in[2];
  const void* mask_raw = d_in[3];
  const float* Wq = (const float*)d_in[4];
  const float* bq = (const float*)d_in[5];
  const float* Wk = (const float*)d_in[6];
  const float* bk = (const float*)d_in[7];
  const float* Wv = (const float*)d_in[8];
  const float* bv = (const float*)d_in[9];
  const float* Wo = (const float*)d_in[10];
  const float* bo = (const float*)d_in[11];
  float* out = (float*)d_out;

  char* ws = (char*)d_ws;
  // layout (bytes); aliasing is safe: qb dead after gemm-Q (att reuses it),
  // kb/vb dead after gemm-K/V (vT reuses that region).
  bf16* qb  = (bf16*)(ws + 0);          // 4096x1024   [0, 8388608)
  bf16* att = qb;                       // alias
  bf16* kb  = (bf16*)(ws + 8388608);    // 8192x768    [8388608, 20971520)
  bf16* vb  = (bf16*)(ws + 20971520);   // 8192x768    [20971520, 33554432)
  bf16* vT  = (bf16*)(ws + 16777216);   // 4x16x64x2048 [16777216, 33554432) alias
  bf16* WqT = (bf16*)(ws + 33554432);   // 1024x1024
  bf16* WkT = (bf16*)(ws + 35651584);   // 1024x768
  bf16* WvT = (bf16*)(ws + 37224448);   // 1024x768
  bf16* WoT = (bf16*)(ws + 38797312);   // 1024x1024
  bf16* qp  = (bf16*)(ws + 40894464);   // 4096x1024
  bf16* kp  = (bf16*)(ws + 49283072);   // 8192x1024
  bf16* vp  = (bf16*)(ws + 66060288);   // 8192x1024
  int*  mnorm = (int*)(ws + 82837504);  // 8192 ints  (end 82870272)

  // normalize mask (handles 1-byte bool or int32 storage)
  mask_prep<<<1, 256, 0, stream>>>(mask_raw, mnorm, B_ * LKV_);

  // convert activations to bf16
  cvt_f32_to_bf16<<<4096, 256, 0, stream>>>(query, qb, (B_ * LQ_ * QDIM_) / 4);
  cvt_f32_to_bf16<<<6144, 256, 0, stream>>>(key, kb, (B_ * LKV_ * KDIM_) / 4);
  cvt_f32_to_bf16<<<6144, 256, 0, stream>>>(value, vb, (B_ * LKV_ * KDIM_) / 4);

  // transpose + convert weights: W[K][N] -> WT[N][K]
  wtrans<<<dim3(16, 16), 256, 0, stream>>>(Wq, WqT, QDIM_, ODIM_);
  wtrans<<<dim3(16, 12), 256, 0, stream>>>(Wk, WkT, KDIM_, ODIM_);
  wtrans<<<dim3(16, 12), 256, 0, stream>>>(Wv, WvT, KDIM_, ODIM_);
  wtrans<<<dim3(16, 16), 256, 0, stream>>>(Wo, WoT, ODIM_, ODIM_);

  // projections
  gemm_bt<1><<<dim3(8, 32), 256, 0, stream>>>(qb, WqT, bq, qp,
                                              B_ * LQ_, ODIM_, QDIM_);
  gemm_bt<1><<<dim3(8, 64), 256, 0, stream>>>(kb, WkT, bk, kp,
                                              B_ * LKV_, ODIM_, KDIM_);
  gemm_bt<1><<<dim3(8, 64), 256, 0, stream>>>(vb, WvT, bv, vp,
                                              B_ * LKV_, ODIM_, KDIM_);

  // V -> V^T per head
  vtrans<<<dim3(32, 16, 4), 256, 0, stream>>>(vp, vT);

  // attention
  attn_kernel<<<dim3(8, 16, 4), 256, 0, stream>>>(qp, kp, vT, mnorm, att);

  // output projection (fp32 out + bias)
  gemm_bt<0><<<dim3(8, 32), 256, 0, stream>>>(att, WoT, bo, out,
                                              B_ * LQ_, ODIM_, ODIM_);
}